// Round 6
// baseline (90.325 us; speedup 1.0000x reference)
//
#include <hip/hip_runtime.h>
#include <hip/hip_bf16.h>
#include <math.h>

#define BH_ 32
#define N_ 4096
#define D_ 64
#define SAMP_ 256
#define SCALE_ 0.125f
#define LOG16_ 2.7725887222397811f
#define HPAD 68

typedef __attribute__((ext_vector_type(4))) float f32x4;
typedef __attribute__((ext_vector_type(8))) short bf16x8;
typedef __attribute__((ext_vector_type(4))) short bf16x4;

static __device__ __forceinline__ unsigned pack2(float a, float b) {
    union { __hip_bfloat162 h; unsigned u; } c;
    c.h = __float22bfloat162_rn(make_float2(a, b));
    return c.u;
}

static __device__ __forceinline__ bf16x8 cvt8v(f32x4 a, f32x4 b) {
    union { unsigned u[4]; bf16x8 v; } r;
    r.u[0] = pack2(a[0], a[1]); r.u[1] = pack2(a[2], a[3]);
    r.u[2] = pack2(b[0], b[1]); r.u[3] = pack2(b[2], b[3]);
    return r.v;
}

static __device__ __forceinline__ bf16x8 cvt8(const float* p) {
    return cvt8v(*(const f32x4*)p, *(const f32x4*)(p + 4));
}

// ---------------- 1. LSH hash (R3 version, working) -------------------------
__global__ __launch_bounds__(128) void hash_kernel(
    const float* __restrict__ q, const float* __restrict__ k,
    const float* __restrict__ pd,
    unsigned char* __restrict__ qbuck, unsigned char* __restrict__ kbuck)
{
    extern __shared__ char smraw[];
    float*  Xs  = (float*)smraw;
    double* Pdl = (double*)(smraw + 128 * HPAD * 4);

    int tid = threadIdx.x;
    const float* src = blockIdx.y ? k : q;
    unsigned char* dst = blockIdx.y ? kbuck : qbuck;
    size_t tok0 = (size_t)blockIdx.x * 128;

    {
        int d = tid >> 1, r0 = (tid & 1) * 4;
#pragma unroll
        for (int j = 0; j < 4; ++j)
            Pdl[d * 8 + r0 + j] = (double)pd[d * 8 + r0 + j];
    }
    {
        const float4* src4 = (const float4*)(src + tok0 * D_);
        for (int i = tid; i < 128 * 16; i += 128) {
            int r = i >> 4, c = i & 15;
            *(float4*)&Xs[r * HPAD + c * 4] = src4[i];
        }
    }
    __syncthreads();

    float xr[64];
#pragma unroll
    for (int c = 0; c < 16; ++c)
        *(float4*)&xr[c * 4] = *(const float4*)&Xs[tid * HPAD + c * 4];

    double acc[8];
#pragma unroll
    for (int r = 0; r < 8; ++r) acc[r] = 0.0;
#pragma unroll
    for (int d = 0; d < 64; ++d) {
        double x = (double)xr[d];
        const double* pr = Pdl + d * 8;
#pragma unroll
        for (int r = 0; r < 8; ++r) acc[r] += x * pr[r];
    }
    int bin = 0;
#pragma unroll
    for (int r = 0; r < 8; ++r)
        if (acc[r] > 0.0) bin |= (1 << r);
    dst[tok0 + tid] = (unsigned char)(bin ^ (bin >> 1));
}

// ---------------- 2. stable counting sort (256 threads) ---------------------
__global__ __launch_bounds__(256) void sort_kernel(
    const unsigned char* __restrict__ qbuck,
    const unsigned char* __restrict__ kbuck,
    int* __restrict__ q_idx, int* __restrict__ k_idx)
{
    __shared__ unsigned short hist[64][256];          // 32 KB
    __shared__ unsigned int   binstart[256];
    __shared__ alignas(16) unsigned char bl[N_];

    int bh = blockIdx.x, tensor = blockIdx.y;
    const unsigned char* buck = (tensor ? kbuck : qbuck) + bh * N_;
    int* idx_out = (tensor ? k_idx : q_idx) + bh * N_;
    int t = threadIdx.x;

    ((uint4*)bl)[t] = ((const uint4*)buck)[t];        // 256 x 16B = 4096
    {
        uint4* h4 = (uint4*)&hist[0][0];              // 2048 uint4
        for (int i = t; i < 2048; i += 256) h4[i] = make_uint4(0, 0, 0, 0);
    }
    __syncthreads();

    // phase 1: per-owner histogram (owner t<64, tokens ascending -> stable)
    if (t < 64) {
        for (int u = 0; u < 64; ++u) hist[t][bl[t * 64 + u]]++;
    }
    __syncthreads();

    // phase 2: column scan, one bin per thread (256-way parallel)
    {
        unsigned run = 0;
        for (int tt = 0; tt < 64; ++tt) {
            unsigned c = hist[tt][t];
            hist[tt][t] = (unsigned short)run;
            run += c;
        }
        binstart[t] = run;
    }
    __syncthreads();

    // exclusive scan of 256 bin counts: 64 lanes x 4 bins + wave prefix
    if (t < 64) {
        unsigned b0 = binstart[t*4], b1 = binstart[t*4+1],
                 b2 = binstart[t*4+2], b3 = binstart[t*4+3];
        unsigned s = b0 + b1 + b2 + b3, p = s;
#pragma unroll
        for (int d = 1; d < 64; d <<= 1) {
            unsigned y = __shfl_up(p, d);
            if (t >= d) p += y;
        }
        unsigned e = p - s;
        binstart[t*4]   = e;
        binstart[t*4+1] = e + b0;
        binstart[t*4+2] = e + b0 + b1;
        binstart[t*4+3] = e + b0 + b1 + b2;
    }
    __syncthreads();

    // phase 3: stable scatter
    if (t < 64) {
        for (int u = 0; u < 64; ++u) {
            int tok = t * 64 + u;
            int b = bl[tok];
            int pos = (int)(binstart[b] + hist[t][b]);
            hist[t][b]++;
            idx_out[pos] = tok;
        }
    }
}

// ---------------- 3. fused attention: 16 waves x 16 queries -----------------
// 512 wgs x 1024 thr (16 waves). Wave w owns queries blk*256 + w*16 .. +15.
// 4 chunk rounds [P1C0,P1C1,P2C0,P2C1], single-buffered 32KB LDS; 32 waves/CU
// (100% occupancy) hides stage latency via TLP. Residual weight folded into
// pass-2 exp bias; out = o / l (exact combine).
// K LDS: [kt(8)][ks(2)][lg(4)][ll(16)][8] shorts; staging thread u writes
// bf16x8 at Ksm[u*8] == K[kidx[(u>>7)*16+(u&15)]][((u>>6)&1)*32+((u>>4)&3)*8..].
// V LDS: [g(32)][d2(4)][r2(4)][16d] subtiles for ds_read_b64_tr_b16.
static __device__ __forceinline__ void compute_chunk16(
    const short* __restrict__ Ks, unsigned vtr, float bias,
    const bf16x8 (&qf)[2], int ll, int lg,
    f32x4 (&o)[4], float& lsum)
{
#pragma unroll
    for (int ks2 = 0; ks2 < 4; ++ks2) {
        unsigned pbu[4];
#pragma unroll
        for (int t = 0; t < 2; ++t) {
            int kt = ks2 * 2 + t;
            f32x4 s = {0.f, 0.f, 0.f, 0.f};
#pragma unroll
            for (int ks = 0; ks < 2; ++ks) {
                bf16x8 a = *(const bf16x8*)&Ks[kt * 1024 + ks * 512 + lg * 128 + ll * 8];
                s = __builtin_amdgcn_mfma_f32_16x16x32_bf16(a, qf[ks], s, 0, 0, 0);
            }
            f32x4 e;
#pragma unroll
            for (int r = 0; r < 4; ++r) e[r] = __expf(fmaf(s[r], SCALE_, bias));
            lsum += (e[0] + e[1]) + (e[2] + e[3]);
            pbu[t*2]   = pack2(e[0], e[1]);
            pbu[t*2+1] = pack2(e[2], e[3]);
        }
        bf16x8 pb;
        { union { unsigned u[4]; bf16x8 v; } c;
          c.u[0]=pbu[0]; c.u[1]=pbu[1]; c.u[2]=pbu[2]; c.u[3]=pbu[3]; pb = c.v; }

        bf16x4 tr[4][2];
#pragma unroll
        for (int dt = 0; dt < 4; ++dt) {
            asm volatile("ds_read_b64_tr_b16 %0, %1 offset:%2"
                         : "=v"(tr[dt][0]) : "v"(vtr), "i"(ks2 * 4096 + dt * 128));
            asm volatile("ds_read_b64_tr_b16 %0, %1 offset:%2"
                         : "=v"(tr[dt][1]) : "v"(vtr), "i"(ks2 * 4096 + dt * 128 + 2048));
        }
        asm volatile("s_waitcnt lgkmcnt(0)" ::: "memory");
        __builtin_amdgcn_sched_barrier(0);
#pragma unroll
        for (int dt = 0; dt < 4; ++dt) {
            union { bf16x4 h[2]; bf16x8 v; } va;
            va.h[0] = tr[dt][0]; va.h[1] = tr[dt][1];
            o[dt] = __builtin_amdgcn_mfma_f32_16x16x32_bf16(va.v, pb, o[dt], 0, 0, 0);
        }
    }
}

__global__ __launch_bounds__(1024, 8) void fused_attn(
    const float* __restrict__ query, const float* __restrict__ key,
    const float* __restrict__ value, const int* __restrict__ q_idx,
    const int* __restrict__ k_idx, const int* __restrict__ sampled,
    float* __restrict__ out)
{
    __shared__ short Ksm[8192];   // 16 KB
    __shared__ short Vsm[8192];   // 16 KB
    int wg = blockIdx.x, bh = wg >> 4, blk = wg & 15;
    int tid = threadIdx.x, w = tid >> 6, l = tid & 63, lg = l >> 4, ll = l & 15;
    size_t base = (size_t)bh * N_;

    // staging decomposition (1024-thread exact cover of 128 keys x 64 d)
    int s_krow = ((tid >> 7) << 4) | (tid & 15);
    int s_kd   = ((tid >> 6) & 1) * 32 + ((tid >> 4) & 3) * 8;
    int s_vrow = ((tid >> 5) << 2) | ((tid >> 1) & 3);
    int s_vd   = ((tid >> 3) & 3) * 16 + (tid & 1) * 8;

    // preload all 4 chunks' gather indices
    const int* kidxA = k_idx + base + blk * 256;
    const int* kidxB = sampled + bh * SAMP_;
    int kI0 = kidxA[s_krow], kI1 = kidxA[128 + s_krow];
    int kI2 = kidxB[s_krow], kI3 = kidxB[128 + s_krow];
    int vI0 = kidxA[s_vrow], vI1 = kidxA[128 + s_vrow];
    int vI2 = kidxB[s_vrow], vI3 = kidxB[128 + s_vrow];

    // Q fragment (gathered by sorted order), loaded once
    const int* qidx = q_idx + base + blk * 256 + w * 16;
    int qr = qidx[ll];
    const float* qp = query + (base + (size_t)qr) * D_ + lg * 8;
    bf16x8 qf[2] = { cvt8(qp), cvt8(qp + 32) };

    f32x4 o[4];
#pragma unroll
    for (int dt = 0; dt < 4; ++dt) { f32x4 z = {0.f,0.f,0.f,0.f}; o[dt] = z; }
    float lsum = 0.f;
    unsigned vtr = (unsigned)(unsigned long long)(void*)&Vsm[0] + lg * 512 + ll * 8;

#define STAGE_(KI, VI) do { \
        const float* kp_ = key   + (base + (size_t)(KI)) * D_ + s_kd; \
        const float* vp_ = value + (base + (size_t)(VI)) * D_ + s_vd; \
        bf16x8 kv_ = cvt8(kp_), vv_ = cvt8(vp_); \
        *(bf16x8*)&Ksm[tid * 8] = kv_; \
        *(bf16x8*)&Vsm[tid * 8] = vv_; } while (0)

    STAGE_(kI0, vI0); __syncthreads();
    compute_chunk16(Ksm, vtr, 0.f, qf, ll, lg, o, lsum);
    __syncthreads(); STAGE_(kI1, vI1); __syncthreads();
    compute_chunk16(Ksm, vtr, 0.f, qf, ll, lg, o, lsum);
    __syncthreads(); STAGE_(kI2, vI2); __syncthreads();
    compute_chunk16(Ksm, vtr, LOG16_, qf, ll, lg, o, lsum);
    __syncthreads(); STAGE_(kI3, vI3); __syncthreads();
    compute_chunk16(Ksm, vtr, LOG16_, qf, ll, lg, o, lsum);
#undef STAGE_

    // row-sum across the 4 lg groups
    lsum += __shfl_xor(lsum, 16);
    lsum += __shfl_xor(lsum, 32);

    // out = o / l; lane (lg,ll) holds query w*16+ll, d = dt*16 + lg*4 + r
    float dn = 1.f / lsum;
    float* orow = out + (base + (size_t)qr) * D_ + lg * 4;
#pragma unroll
    for (int dt = 0; dt < 4; ++dt) {
        f32x4 v = o[dt] * dn;
        *(f32x4*)&orow[dt * 16] = v;
    }
}

// ---------------------------------------------------------------------------
extern "C" void kernel_launch(void* const* d_in, const int* in_sizes, int n_in,
                              void* d_out, int out_size, void* d_ws, size_t ws_size,
                              hipStream_t stream)
{
    const float* query = (const float*)d_in[0];
    const float* key   = (const float*)d_in[1];
    const float* value = (const float*)d_in[2];
    const float* pd    = (const float*)d_in[3];
    const int*   samp  = (const int*)d_in[4];
    float* out = (float*)d_out;

    char* ws = (char*)d_ws;
    unsigned char* qbuck = (unsigned char*)ws;                 // 128 KB
    unsigned char* kbuck = qbuck + (size_t)BH_ * N_;           // 128 KB
    int* q_idx = (int*)(ws + 262144);                          // 512 KB
    int* k_idx = (int*)(ws + 262144 + 524288);                 // 512 KB

    size_t hash_lds = 128 * HPAD * 4 + 512 * 8;
    hipLaunchKernelGGL(hash_kernel, dim3(BH_ * N_ / 128, 2), dim3(128),
                       hash_lds, stream, query, key, pd, qbuck, kbuck);
    hipLaunchKernelGGL(sort_kernel, dim3(BH_, 2), dim3(256), 0, stream,
                       qbuck, kbuck, q_idx, k_idx);
    hipLaunchKernelGGL(fused_attn, dim3(512), dim3(1024), 0, stream,
                       query, key, value, q_idx, k_idx, samp, out);
}